// Round 2
// 98.150 us; speedup vs baseline: 1.1259x; 1.1259x over previous
//
#include <hip/hip_runtime.h>

#define NQ 32768
#define NC 8192
#define CFEAT 128
#define CSPLIT 64
#define TILE (NC / CSPLIT)   // 128 coords per split
#define BLK 256
#define QPT 4                // queries per thread
#define QPB (BLK * QPT)      // 1024 queries per block

// ws layout: [0, 8 MB) f32 bestd[NQ][CSPLIT]; then float4 ctab[NC] (128 KB).
// ctab is written by phase 1 (blockIdx.x==0 blocks) and read by phase 2, so
// BOTH phases consume the exact same stored bits — the equality rescan in
// phase 2 is structurally guaranteed to hit (R0-proven configuration).
// R1 lesson: computing the ctab formula independently in two kernels is NOT
// bit-safe — hipcc's -ffp-contract=fast may fuse the cc mul+add pairs into
// v_fma differently per kernel. __f*_rn intrinsics do not block contraction.
#define BESTD_OFF 0
#define CTAB_OFF ((size_t)NQ * CSPLIT * 4)

// Phase 1: per-split min DISTANCE only — no index tracking.
// Folds the old init_ctab kernel in as a 2 KB LDS stage (threads 0..127);
// blockIdx.x==0 additionally persists the staged bits to global ctab for
// phase 2. cc order pinned via asm barriers to np's sum order:
//   cc = ((cx*cx + cy*cy) + cz*cz), each op RN, no fma contraction possible.
// Inner loop min3-paired: per 2 coords per query
//   {mul,fma,fma,add} x2 + v_min3_f32 = 9 VALU -> ~15.3 us VALU floor.
// The distance chain (mul,fma,fma,add on stored ctab bits) has no
// contraction freedom -> compiles identically in phase 1 and phase 2.
__global__ __launch_bounds__(BLK, 8) void argmin_split(
    const float* __restrict__ coords, const float* __restrict__ points,
    float* __restrict__ bestd, float4* __restrict__ ctab) {
  __shared__ float4 ctab_s[TILE];

  const int s = blockIdx.y;
  const int base = s * TILE;

  // Stage this split's coord table into LDS (threads 0..127).
  if (threadIdx.x < TILE) {
    const int i = base + threadIdx.x;
    const float cx = coords[i * 3 + 0];
    const float cy = coords[i * 3 + 1];
    const float cz = coords[i * 3 + 2];
    float xx = cx * cx, yy = cy * cy, zz = cz * cz;
    // Opaque barrier: forbid fusing these products into the adds below, in
    // every compilation of this formula. Order = np.sum(coords*coords, -1).
    asm volatile("" : "+v"(xx), "+v"(yy), "+v"(zz));
    const float cc = (xx + yy) + zz;
    const float4 e = make_float4(-2.0f * cx, -2.0f * cy, -2.0f * cz, cc);
    ctab_s[threadIdx.x] = e;
    if (blockIdx.x == 0) ctab[i] = e;   // persist exact bits for phase 2
  }

  const int q0 = blockIdx.x * QPB + threadIdx.x;
  float px[QPT], py[QPT], pz[QPT], best[QPT];
  #pragma unroll
  for (int k = 0; k < QPT; ++k) {
    const int q = q0 + k * BLK;
    px[k] = points[q * 3 + 0];
    py[k] = points[q * 3 + 1];
    pz[k] = points[q * 3 + 2];
    best[k] = __builtin_inff();
  }
  __syncthreads();

  #pragma unroll 4
  for (int i = 0; i < TILE; i += 2) {
    const float4 c0 = ctab_s[i];     // uniform addr -> ds_read_b128 broadcast
    const float4 c1 = ctab_s[i + 1];
    #pragma unroll
    for (int k = 0; k < QPT; ++k) {
      float t0 = __fmul_rn(c0.x, px[k]);
      t0 = __fmaf_rn(c0.y, py[k], t0);
      t0 = __fmaf_rn(c0.z, pz[k], t0);
      const float d0 = __fadd_rn(c0.w, t0);
      float t1 = __fmul_rn(c1.x, px[k]);
      t1 = __fmaf_rn(c1.y, py[k], t1);
      t1 = __fmaf_rn(c1.z, pz[k], t1);
      const float d1 = __fadd_rn(c1.w, t1);
      best[k] = fminf(fminf(best[k], d0), d1);   // fuses to v_min3_f32
    }
  }

  #pragma unroll
  for (int k = 0; k < QPT; ++k) {
    const int q = q0 + k * BLK;
    bestd[(size_t)q * CSPLIT + s] = best[k];
  }
}

// Phase 2 (one wave per query, fused): reduce 64 split-mins -> global min +
// lowest winning split (ballot/ffs = lowest lane on value ties); rescan that
// split's 128 coords from the SHARED global ctab (same bits phase 1 used,
// same contraction-free chain -> equality hit guaranteed; first match =
// lowest index). Tiebreak chain == np.argmin's global first-index.
// Then gather the 128-float feature row with 64 lanes x float2.
__global__ __launch_bounds__(256) void rescan_gather(
    const float4* __restrict__ ctab, const float* __restrict__ points,
    const float* __restrict__ bestd, const float* __restrict__ feature,
    float2* __restrict__ out) {
  const int q = blockIdx.x * 4 + (threadIdx.x >> 6);
  const int l = threadIdx.x & 63;

  // lane l holds split l's min — 256 B coalesced read per wave
  const float v = bestd[(size_t)q * CSPLIT + l];
  float m = v;
  #pragma unroll
  for (int off = 32; off; off >>= 1) m = fminf(m, __shfl_xor(m, off, 64));
  const unsigned long long bs = __ballot(v == m);
  const int sstar = __ffsll(bs) - 1;            // lowest split attaining min

  const float px = points[q * 3 + 0];           // wave-uniform
  const float py = points[q * 3 + 1];
  const float pz = points[q * 3 + 2];
  const int base = sstar * TILE;

  const float4 c0 = ctab[base + l];             // coalesced, lanes consecutive
  const float4 c1 = ctab[base + 64 + l];
  float t0 = __fmul_rn(c0.x, px);
  t0 = __fmaf_rn(c0.y, py, t0);
  t0 = __fmaf_rn(c0.z, pz, t0);
  const float d0 = __fadd_rn(c0.w, t0);
  float t1 = __fmul_rn(c1.x, px);
  t1 = __fmaf_rn(c1.y, py, t1);
  t1 = __fmaf_rn(c1.z, pz, t1);
  const float d1 = __fadd_rn(c1.w, t1);

  const unsigned long long b0 = __ballot(d0 == m);
  const unsigned long long b1 = __ballot(d1 == m);
  int off_in;
  if (b0 | b1) {
    off_in = b0 ? (__ffsll(b0) - 1) : (64 + __ffsll(b1) - 1);
  } else {
    // Defense in depth (should be unreachable): true argmin over the 128
    // rescanned candidates, first-index tiebreak.
    float dm = fminf(d0, d1);
    int im = (d0 <= d1) ? l : (64 + l);
    #pragma unroll
    for (int off = 32; off; off >>= 1) {
      const float od = __shfl_xor(dm, off, 64);
      const int oi = __shfl_xor(im, off, 64);
      if (od < dm || (od == dm && oi < im)) { dm = od; im = oi; }
    }
    off_in = im;
  }
  const int idx = base + off_in;

  const float2* fr = (const float2*)(feature + (size_t)idx * CFEAT);
  out[(size_t)q * (CFEAT / 2) + l] = fr[l];
}

extern "C" void kernel_launch(void* const* d_in, const int* in_sizes, int n_in,
                              void* d_out, int out_size, void* d_ws, size_t ws_size,
                              hipStream_t stream) {
  const float* coords  = (const float*)d_in[0];   // [8192, 3]
  const float* feature = (const float*)d_in[1];   // [8192, 128]
  const float* points  = (const float*)d_in[2];   // [32768, 3]
  float* out = (float*)d_out;                     // [32768, 128]

  float* bestd = (float*)((char*)d_ws + BESTD_OFF);
  float4* ctab = (float4*)((char*)d_ws + CTAB_OFF);

  dim3 grid1(NQ / QPB, CSPLIT);                   // (32, 64) = 2048 blocks
  argmin_split<<<grid1, BLK, 0, stream>>>(coords, points, bestd, ctab);

  rescan_gather<<<NQ / 4, 256, 0, stream>>>(ctab, points, bestd, feature,
                                            (float2*)out);
}